// Round 1
// baseline (768.378 us; speedup 1.0000x reference)
//
#include <hip/hip_runtime.h>
#include <hip/hip_bf16.h>
#include <stdint.h>

#define F 128
#define R 6
#define NTYPES 95
#define MTILE 128
#define HPAD 136   // 128 + 8 bf16 pad -> 272B row stride, kills ds_read_b128 bank conflicts

typedef short bf16x8 __attribute__((ext_vector_type(8)));
typedef float floatx4 __attribute__((ext_vector_type(4)));

__device__ __forceinline__ unsigned short f2bf(float x) {
    union { float f; unsigned u; } cv; cv.f = x;
    unsigned u = cv.u;
    return (unsigned short)((u + 0x7FFFu + ((u >> 16) & 1u)) >> 16);  // RNE
}

// swish via v_rcp_f32 (~1 ulp) instead of IEEE div sequence (~10 instrs).
// absmax tolerance is bf16-dominated (0.03); rcp error is negligible here.
__device__ __forceinline__ float swishf(float x) {
    return x * __builtin_amdgcn_rcpf(1.0f + __expf(-x));
}

__device__ __forceinline__ floatx4 swish4(floatx4 v) {
    floatx4 r;
    #pragma unroll
    for (int i = 0; i < 4; ++i) r[i] = swishf(v[i]);
    return r;
}

// blocks 0..94:  embW[z][0:128]=emb[z]@W[0:128] + b  (bias folded in),
//                embW[z][128:256]=emb[z]@W[128:256]  (fp32)
// blocks 95..158: w2t[n][k] = bf16(W[256+k][n])  (transposed K-contiguous for MFMA frags)
__global__ void prep_kernel(const float* __restrict__ emb,
                            const float* __restrict__ W,
                            const float* __restrict__ bvec,
                            float* __restrict__ embW,
                            unsigned short* __restrict__ w2t) {
    int t = threadIdx.x;
    int b = blockIdx.x;
    if (b < NTYPES) {
        int c = t >> 7, f = t & 127;
        const float* er = emb + b * F;
        const float* Wc = W + c * F * F;
        float a = 0.f;
        #pragma unroll 8
        for (int k = 0; k < F; ++k) a = __builtin_fmaf(er[k], Wc[k * F + f], a);
        embW[b * 256 + c * F + f] = a + (c == 0 ? bvec[f] : 0.f);
    } else {
        int idx = (b - NTYPES) * 256 + t;  // 0..16383
        int n = idx >> 7, k = idx & 127;
        w2t[n * F + k] = f2bf(W[(256 + k) * F + n]);
    }
}

__global__ __launch_bounds__(256) void
edge_kernel(const int* __restrict__ Z,
            const float* __restrict__ rbf,
            const int* __restrict__ idnb_i,
            const int* __restrict__ idnb_j,
            const float* __restrict__ W_rbf,
            const float* __restrict__ b_rbf,
            const float* __restrict__ embW,
            const unsigned short* __restrict__ w2t,
            float* __restrict__ out,
            int E) {
    __shared__ __align__(16) short h_bf[MTILE * HPAD]; // 34816 B, rbf_h tile (bf16)
    __shared__ float rbf_s[MTILE * R];
    __shared__ int zi_s[MTILE];
    __shared__ int zj_s[MTILE];

    int t = threadIdx.x;
    int blk = blockIdx.x;
    long ebase = (long)blk * MTILE;

    // ---- stage: rbf (coalesced, 768 floats), Z-gathers (both halves in parallel) ----
    #pragma unroll
    for (int i = 0; i < 3; ++i) {
        int idx = i * 256 + t;
        long g = ebase * R + idx;
        rbf_s[idx] = (g < (long)E * R) ? rbf[g] : 0.f;
    }
    {
        int te = t & 127;
        long e = ebase + te;
        long ec = (e < (long)E) ? e : 0;
        int zz = Z[(t < 128 ? idnb_i : idnb_j)[ec]];
        if (t < 128) zi_s[te] = zz; else zj_s[te] = zz;
    }

    // W_rbf columns for this thread's 2 features (registers)
    int fpair = t & 63;
    int f0 = fpair * 2;
    float wr0[R], wr1[R];
    #pragma unroll
    for (int r = 0; r < R; ++r) {
        wr0[r] = W_rbf[r * F + f0];
        wr1[r] = W_rbf[r * F + f0 + 1];
    }
    float brb0 = b_rbf[f0], brb1 = b_rbf[f0 + 1];

    __syncthreads();

    // ---- compute rbf_h tile -> h_bf (each wave: 32 edges, 2 features/thread) ----
    int eg = t >> 6;
    for (int it = 0; it < 32; ++it) {
        int e = eg * 32 + it;
        const float2* rp2 = (const float2*)(rbf_s + e * R);  // wave-uniform -> LDS broadcast
        float2 qa = rp2[0], qb = rp2[1], qc = rp2[2];
        float rv[R] = {qa.x, qa.y, qb.x, qb.y, qc.x, qc.y};
        float v0 = brb0, v1 = brb1;
        #pragma unroll
        for (int r = 0; r < R; ++r) {
            v0 = __builtin_fmaf(rv[r], wr0[r], v0);
            v1 = __builtin_fmaf(rv[r], wr1[r], v1);
        }
        v0 = swishf(v0); v1 = swishf(v1);
        unsigned packed = (unsigned)f2bf(v0) | ((unsigned)f2bf(v1) << 16);
        *(unsigned*)(&h_bf[e * HPAD + f0]) = packed;
    }

    __syncthreads();

    // ---- MFMA, OPERAND-SWAPPED: D[f][e] = W2^T @ rbf_h^T, 16x16x32 bf16 ----
    // A-frag (lane l15 -> row m): w2t row = output feature  (same data as before)
    // B-frag (lane l15 -> col n): rbf_h row = edge           (same LDS reads as before)
    // C/D: col(l15) = edge, row(quad*4+reg) = feature -> lane holds 4 CONSECUTIVE
    // features of one edge => dwordx4 stores + float4 epilogue gathers.
    int w = t >> 6;
    int lid = t & 63;
    int quad = lid >> 4;
    int l15 = lid & 15;
    int wbase = w * 32;

    floatx4 acc[2][8];
    #pragma unroll
    for (int et = 0; et < 2; ++et)
        #pragma unroll
        for (int ft = 0; ft < 8; ++ft)
            acc[et][ft] = (floatx4){0.f, 0.f, 0.f, 0.f};

    const bf16x8* w2v = (const bf16x8*)w2t;  // [n][k] rows of 128 bf16 = 16 chunks
    #pragma unroll
    for (int ks = 0; ks < 4; ++ks) {
        bf16x8 b0 = *(const bf16x8*)(&h_bf[(wbase + l15) * HPAD + ks * 32 + quad * 8]);
        bf16x8 b1 = *(const bf16x8*)(&h_bf[(wbase + 16 + l15) * HPAD + ks * 32 + quad * 8]);
        #pragma unroll
        for (int ft = 0; ft < 8; ++ft) {
            bf16x8 afr = w2v[(ft * 16 + l15) * 16 + ks * 4 + quad];  // L1-resident 32KB
            acc[0][ft] = __builtin_amdgcn_mfma_f32_16x16x32_bf16(afr, b0, acc[0][ft], 0, 0, 0);
            acc[1][ft] = __builtin_amdgcn_mfma_f32_16x16x32_bf16(afr, b1, acc[1][ft], 0, 0, 0);
        }
    }

    // ---- epilogue: + embW0[zi] + embW1[zj] (bias pre-folded), swish, dwordx4 store ----
    #pragma unroll
    for (int et = 0; et < 2; ++et) {
        int e_loc = wbase + et * 16 + l15;
        long e_g = ebase + e_loc;
        bool ok = e_g < (long)E;
        int zi = zi_s[e_loc], zj = zj_s[e_loc];
        const floatx4* p0 = (const floatx4*)(embW + zi * 256);      // x1 @ W0 + b
        const floatx4* p1 = (const floatx4*)(embW + zj * 256 + F);  // x2 @ W1
        float* op = out + e_g * F;
        #pragma unroll
        for (int ft = 0; ft < 8; ++ft) {
            int f4 = ft * 4 + quad;  // float4 index; f = ft*16 + quad*4
            floatx4 v = acc[et][ft] + p0[f4] + p1[f4];
            floatx4 r = swish4(v);
            if (ok) *(floatx4*)(op + f4 * 4) = r;
        }
    }
}

extern "C" void kernel_launch(void* const* d_in, const int* in_sizes, int n_in,
                              void* d_out, int out_size, void* d_ws, size_t ws_size,
                              hipStream_t stream) {
    const int*   Z     = (const int*)d_in[0];
    const float* rbf   = (const float*)d_in[1];
    const int*   id_i  = (const int*)d_in[2];
    const int*   id_j  = (const int*)d_in[3];
    const float* emb   = (const float*)d_in[4];
    const float* W_rbf = (const float*)d_in[5];
    const float* b_rbf = (const float*)d_in[6];
    const float* W     = (const float*)d_in[7];
    const float* bvec  = (const float*)d_in[8];
    float* out = (float*)d_out;
    int E = in_sizes[2];

    float* embW = (float*)d_ws;                                   // 95*256*4 = 97280 B
    unsigned short* w2t = (unsigned short*)((char*)d_ws + 97280); // 128*128*2 = 32768 B

    prep_kernel<<<NTYPES + 64, 256, 0, stream>>>(emb, W, bvec, embW, w2t);
    int grid = (E + MTILE - 1) / MTILE;
    edge_kernel<<<grid, 256, 0, stream>>>(Z, rbf, id_i, id_j, W_rbf, b_rbf,
                                          embW, w2t, out, E);
}